// Round 10
// baseline (163.446 us; speedup 1.0000x reference)
//
#include <hip/hip_runtime.h>
#include <cstdint>
#include <cstddef>

typedef __bf16 bf16;
typedef __attribute__((ext_vector_type(2))) __bf16 bf16x2;
typedef __attribute__((ext_vector_type(8))) __bf16 bf16x8;
typedef __attribute__((ext_vector_type(2))) float f32x2;
typedef __attribute__((ext_vector_type(4))) float f32x4;

#define EPS_C 1e-4f
#define SWZ(r) (((r) ^ ((r) >> 2)) & 3)

// light barrier: LDS visibility only, vmem loads stay in flight
#define BAR_LDS() do { asm volatile("s_waitcnt lgkmcnt(0)" ::: "memory"); \
                       __builtin_amdgcn_s_barrier(); } while (0)

// ================= K0: weights prep =================
// Whg: reduced in_proj hi bf16, COLUMN-PERMUTED (wave-balanced: each 48-col group =
// 16 delta + 16 Bmean + 16 Cmean), chunk-major [k/32][n_new][k%32].
// Wlg: lo-part of the 64 delta rows only, [k/32][d][k%32].
// Wob: out_proj bf16 [dm][i]. cwp: conv weights bf16 [ch][4]. cbl: conv bias f32.
__global__ __launch_bounds__(256) void k0_prep(const float* __restrict__ Wi,
    const float* __restrict__ Wo, const float* __restrict__ cw, const float* __restrict__ cb,
    bf16* __restrict__ Whg, bf16* __restrict__ Wlg, bf16* __restrict__ Wob,
    bf16* __restrict__ cwp, float* __restrict__ cbl, float* __restrict__ zpg)
{
    int idx = blockIdx.x * 256 + threadIdx.x;
    if (idx < 196608) {
        int nn = idx >> 10, k = idx & 1023;
        int wn = nn / 48, s = nn - wn * 48;
        if (s < 16) {
            int d = wn * 16 + s;
            float w = Wi[d * 1024 + k];
            bf16 h = (bf16)w;
            Whg[(k >> 5) * 6144 + nn * 32 + (k & 31)] = h;
            Wlg[(k >> 5) * 2048 + d * 32 + (k & 31)] = (bf16)(w - (float)h);
        } else if (s < 32) {
            int i = wn * 16 + (s - 16);
            float w = 0.5f * (Wi[(64 + 2 * i) * 1024 + k] + Wi[(65 + 2 * i) * 1024 + k]);
            Whg[(k >> 5) * 6144 + nn * 32 + (k & 31)] = (bf16)w;
        } else {
            int i = wn * 16 + (s - 32);
            float w = 0.5f * (Wi[(192 + 2 * i) * 1024 + k] + Wi[(193 + 2 * i) * 1024 + k]);
            Whg[(k >> 5) * 6144 + nn * 32 + (k & 31)] = (bf16)w;
        }
    } else if (idx < 262144) {
        int j = idx - 196608;
        Wob[j] = (bf16)Wo[j];
    } else if (idx < 266240) {
        int j = idx - 262144;                 // cwp[ch*4+tap]
        cwp[j] = (bf16)cw[j];
    } else if (idx < 267264) {
        int j = idx - 266240;
        cbl[j] = cb[j];
    } else {
        int j = idx - 267264;
        if (j < 1024) zpg[j] = 0.f;
    }
}

// ================= K1: conv + MFMA in_proj (delta 3-pass, B/C 2-pass) + SSM + scan =================
// 256 threads (4 waves), t-tile 16, grid 2048 (8 blocks/CU target, ~6 resident).
// Wave: 16t x 48n (16 delta + 16 B + 16 C cols). LDS 16 KB. One light barrier/chunk.
__global__ __launch_bounds__(256, 6) void k1_convproj(
    const float* __restrict__ x, const float* __restrict__ in_proj_b,
    const float* __restrict__ A_log,
    const bf16* __restrict__ Whg, const bf16* __restrict__ Wlg,
    const bf16* __restrict__ cwp_g, const float* __restrict__ cbl_g,
    const float* __restrict__ zpg,
    float* __restrict__ Yp, float* __restrict__ Zp,
    float* __restrict__ Psum, float* __restrict__ Ssum)
{
    __shared__ char smem[16384];
    // xch[2] @0 (2x1024) | xcl[2] @2048 | cwp @4096 (8192) | cbl @12288 (4096)
    // epilogue overlay: res[16][196] f32 @0 (12544) | part @12544 (2048)

    const int tid  = threadIdx.x;
    const int lane = tid & 63;
    const int wn   = tid >> 6;
    const int fr   = lane & 15, fs = lane >> 4;
    const int b    = blockIdx.x >> 8;
    const int tc   = blockIdx.x & 255;
    const int t0   = tc * 16;

    // conv mapping: thread -> (row ct 0..15, channel pair cs 0..15)
    const int ct = tid >> 4, cs = tid & 15;
    const int gt = t0 + ct;
    const bool zrow = (gt == 4095);          // reference zero-pads last conv row

    const int woff = ct * 64 + ((((cs >> 2) ^ SWZ(ct)) & 3) << 4) + (cs & 3) * 4;
    const int aoff = fr * 64 + ((fs ^ SWZ(fr)) << 4);

    const float* rp[4];
#pragma unroll
    for (int dt = 0; dt < 4; ++dt) {
        int g = gt - 1 + dt;
        rp[dt] = (g >= 0 && g < 4096) ? x + ((size_t)b * 4096 + g) * 1024 + cs * 2
                                      : zpg + cs * 2;
    }

    // ---- stage conv tables to LDS ----
    {
        uint2* cwl = (uint2*)(smem + 4096);
        float* cbll = (float*)(smem + 12288);
#pragma unroll
        for (int p = tid; p < 1024; p += 256)
            cwl[p] = ((const uint2*)cwp_g)[p];
        ((f32x4*)cbll)[tid] = ((const f32x4*)cbl_g)[tid];
    }

    f32x2  xr[4];
    bf16x8 wh[3], wl;
    f32x4  acc[3] = {};

    auto fetch_x = [&](int c) {
#pragma unroll
        for (int dt = 0; dt < 4; ++dt)
            xr[dt] = *(const f32x2*)(rp[dt] + c * 32);
    };
    auto fetch_w = [&](int c) {
        const bf16* ph = Whg + (size_t)c * 6144 + (wn * 48 + fr) * 32 + fs * 8;
#pragma unroll
        for (int ni = 0; ni < 3; ++ni)
            wh[ni] = *(const bf16x8*)(ph + ni * 512);
        wl = *(const bf16x8*)(Wlg + (size_t)c * 2048 + (wn * 16 + fr) * 32 + fs * 8);
    };
    auto conv = [&](int c) {                 // xr -> xc buf[c&1]
        const bf16*  cwl  = (const bf16*)(smem + 4096);
        const float* cbll = (const float*)(smem + 12288);
        char* dh = smem + (c & 1) * 1024;
        char* dl = smem + 2048 + (c & 1) * 1024;
        const int ch0 = c * 32 + cs * 2;
        bf16x8 wt = *(const bf16x8*)(cwl + ch0 * 4);   // broadcast across ct groups
        f32x2 bias = *(const f32x2*)(cbll + ch0);
        float v0 = bias.x, v1 = bias.y;
        v0 = fmaf((float)wt[0], xr[0].x, v0);
        v0 = fmaf((float)wt[1], xr[1].x, v0);
        v0 = fmaf((float)wt[2], xr[2].x, v0);
        v0 = fmaf((float)wt[3], xr[3].x, v0);
        v1 = fmaf((float)wt[4], xr[0].y, v1);
        v1 = fmaf((float)wt[5], xr[1].y, v1);
        v1 = fmaf((float)wt[6], xr[2].y, v1);
        v1 = fmaf((float)wt[7], xr[3].y, v1);
        if (zrow) { v0 = 0.f; v1 = 0.f; }
        bf16 h0 = (bf16)v0, h1 = (bf16)v1;
        bf16x2 hp, lp;
        hp[0] = h0; hp[1] = h1;
        lp[0] = (bf16)(v0 - (float)h0); lp[1] = (bf16)(v1 - (float)h1);
        *(bf16x2*)(dh + woff) = hp;
        *(bf16x2*)(dl + woff) = lp;
    };

    // ---- prologue ----
    fetch_x(0);
    fetch_w(0);
    __syncthreads();                         // tables visible
    conv(0);
    fetch_x(1);
    BAR_LDS();                               // xc0 visible

#pragma unroll 1
    for (int c = 0; c < 32; ++c) {
        const char* xh = smem + (c & 1) * 1024;
        const char* xl = smem + 2048 + (c & 1) * 1024;
        bf16x8 ah = *(const bf16x8*)(xh + aoff);
        bf16x8 al = *(const bf16x8*)(xl + aoff);
        if (c + 1 < 32) {
            conv(c + 1);                     // uses xr(c+1), writes buf[(c+1)&1]
            if (c + 2 < 32) fetch_x(c + 2);  // GUARDED: no chunk-32 OOB read
        }
        __builtin_amdgcn_s_setprio(1);
        acc[0] = __builtin_amdgcn_mfma_f32_16x16x32_bf16(ah, wh[0], acc[0], 0, 0, 0);
        acc[1] = __builtin_amdgcn_mfma_f32_16x16x32_bf16(ah, wh[1], acc[1], 0, 0, 0);
        acc[2] = __builtin_amdgcn_mfma_f32_16x16x32_bf16(ah, wh[2], acc[2], 0, 0, 0);
        acc[0] = __builtin_amdgcn_mfma_f32_16x16x32_bf16(al, wh[0], acc[0], 0, 0, 0);
        acc[1] = __builtin_amdgcn_mfma_f32_16x16x32_bf16(al, wh[1], acc[1], 0, 0, 0);
        acc[2] = __builtin_amdgcn_mfma_f32_16x16x32_bf16(al, wh[2], acc[2], 0, 0, 0);
        acc[0] = __builtin_amdgcn_mfma_f32_16x16x32_bf16(ah, wl,    acc[0], 0, 0, 0);
        __builtin_amdgcn_s_setprio(0);
        if (c + 1 < 32) fetch_w(c + 1);      // after last use of wh/wl this body
        BAR_LDS();
    }

    // ---- epilogue: res[16][196], SSM elementwise + chunk-local scan ----
    float* res = (float*)smem;
#pragma unroll
    for (int ni = 0; ni < 3; ++ni) {
        int col = wn * 48 + ni * 16 + fr;
#pragma unroll
        for (int r = 0; r < 4; ++r)
            res[(fs * 4 + r) * 196 + col] = acc[ni][r];
    }
    __syncthreads();

    float* part = (float*)(smem + 12544);    // [2][4][64]
    const int i  = lane;
    const int tg = tid >> 6;
    const float A  = -expf(A_log[i]);
    const float bd = in_proj_b[i];
    const float bB = 0.5f * (in_proj_b[64 + 2 * i] + in_proj_b[65 + 2 * i]);
    const float bC = 0.5f * (in_proj_b[192 + 2 * i] + in_proj_b[193 + 2 * i]);
    const bool tiny = fabsf(A) < EPS_C;
    const int dcol = (i >> 4) * 48 + (i & 15);   // un-permute columns
    float av[4], bv[4], cv[4];
#pragma unroll
    for (int r = 0; r < 4; ++r) {
        int t = tg * 4 + r;
        float d  = res[t * 196 + dcol] + bd;
        float Bm = res[t * 196 + dcol + 16] + bB;
        float Cm = res[t * 196 + dcol + 32] + bC;
        float delta = (d > 20.f) ? d : log1pf(expf(d));
        float dA = delta * A;
        float abar = expf(dA);
        float sc = tiny ? (1.f + dA * 0.5f + dA * dA * (1.f / 6.f)) : ((abar - 1.f) / A);
        av[r] = abar; bv[r] = sc * Bm; cv[r] = Cm;
    }
    float P = 1.f, S = 0.f;
#pragma unroll
    for (int r = 0; r < 4; ++r) { S = fmaf(av[r], S, bv[r]); P *= av[r]; }
    part[tg * 64 + i] = P;
    part[256 + tg * 64 + i] = S;
    __syncthreads();
    float h = 0.f, pp = 1.f;
#pragma unroll
    for (int g = 0; g < 3; ++g)
        if (g < tg) {
            float Pg = part[g * 64 + i], Sg = part[256 + g * 64 + i];
            h = fmaf(Pg, h, Sg);
            pp *= Pg;
        }
    size_t ob = ((size_t)b * 4096 + t0 + tg * 4) * 64 + i;
#pragma unroll
    for (int r = 0; r < 4; ++r) {
        h  = fmaf(av[r], h, bv[r]);
        pp *= av[r];
        Yp[ob + (size_t)r * 64] = cv[r] * h;
        Zp[ob + (size_t)r * 64] = cv[r] * pp;
    }
    if (tg == 3) {
        size_t o = ((size_t)b * 256 + tc) * 64 + i;
        Psum[o] = pp;
        Ssum[o] = h;
    }
}

// ================= K2: serial carry combine across 256 chunks =================
__global__ __launch_bounds__(64) void k2_scan2(const float* __restrict__ Psum,
    const float* __restrict__ Ssum, float* __restrict__ Carry)
{
    int b = blockIdx.x, i = threadIdx.x;
    float h = 0.f;
#pragma unroll 1
    for (int g = 0; g < 16; ++g) {
        size_t base = ((size_t)b * 256 + g * 16) * 64 + i;
        float Pv[16], Sv[16];
#pragma unroll
        for (int j = 0; j < 16; ++j) {
            Pv[j] = Psum[base + (size_t)j * 64];
            Sv[j] = Ssum[base + (size_t)j * 64];
        }
#pragma unroll
        for (int j = 0; j < 16; ++j) {
            Carry[base + (size_t)j * 64] = h;
            h = fmaf(Pv[j], h, Sv[j]);
        }
    }
}

// ================= K3: y = Yp + Zp*carry, fused out_proj MFMA =================
// 512 threads (8 waves). Block = 64-t span; carry is 16-t granular.
__global__ __launch_bounds__(512) void k3_scan_out(
    const float* __restrict__ Yp, const float* __restrict__ Zp,
    const float* __restrict__ Carry, const bf16* __restrict__ Wob,
    const float* __restrict__ bo, float* __restrict__ out)
{
    __shared__ char sm3[8192];               // [64 t][64 i] bf16, swizzled

    const int tid  = threadIdx.x;
    const int lane = tid & 63;
    const int wv   = tid >> 6;
    const int b    = blockIdx.x >> 6;
    const int ch   = blockIdx.x & 63;
    const int t0   = ch * 64;

    const int i = lane, tg = wv;
    float cr = Carry[((size_t)b * 256 + ((t0 + tg * 8) >> 4)) * 64 + i];
    size_t base = ((size_t)(b * 4096) + t0 + tg * 8) * 64 + i;
#pragma unroll
    for (int r = 0; r < 8; ++r) {
        float y = Yp[base + (size_t)r * 64] + Zp[base + (size_t)r * 64] * cr;
        int t = tg * 8 + r;
        int off = t * 128 + ((((i >> 3) ^ (t & 7)) & 7) << 4) + (i & 7) * 2;
        *(bf16*)(sm3 + off) = (bf16)y;
    }
    __syncthreads();

    const int fr = lane & 15, fs = lane >> 4;
    bf16x8 afr[4][2];
#pragma unroll
    for (int mi = 0; mi < 4; ++mi)
#pragma unroll
        for (int ks = 0; ks < 2; ++ks) {
            int row = mi * 16 + fr;
            int slot = ks * 4 + fs;
            int off = row * 128 + (((slot ^ (row & 7)) & 7) << 4);
            afr[mi][ks] = *(const bf16x8*)(sm3 + off);
        }
    const int n0 = wv * 128;
#pragma unroll
    for (int ni = 0; ni < 8; ++ni) {
        int col = n0 + ni * 16 + fr;
        bf16x8 b0 = *(const bf16x8*)(Wob + (size_t)col * 64 + fs * 8);
        bf16x8 b1 = *(const bf16x8*)(Wob + (size_t)col * 64 + 32 + fs * 8);
        float bias = bo[col];
#pragma unroll
        for (int mi = 0; mi < 4; ++mi) {
            f32x4 a = {};
            a = __builtin_amdgcn_mfma_f32_16x16x32_bf16(afr[mi][0], b0, a, 0, 0, 0);
            a = __builtin_amdgcn_mfma_f32_16x16x32_bf16(afr[mi][1], b1, a, 0, 0, 0);
#pragma unroll
            for (int r = 0; r < 4; ++r) {
                int t = mi * 16 + fs * 4 + r;
                out[((size_t)(b * 4096) + t0 + t) * 1024 + col] = a[r] + bias;
            }
        }
    }
}

extern "C" void kernel_launch(void* const* d_in, const int* in_sizes, int n_in,
                              void* d_out, int out_size, void* d_ws, size_t ws_size,
                              hipStream_t stream) {
    const float* x          = (const float*)d_in[0];
    const float* conv_w     = (const float*)d_in[1];
    const float* conv_b     = (const float*)d_in[2];
    const float* in_proj_w  = (const float*)d_in[3];
    const float* in_proj_b  = (const float*)d_in[4];
    const float* A_log      = (const float*)d_in[5];
    const float* out_proj_w = (const float*)d_in[6];
    const float* out_proj_b = (const float*)d_in[7];
    float* out = (float*)d_out;

    char* w = (char*)d_ws;
    bf16*  Whg  = (bf16*)w;                         // 393216
    bf16*  Wlg  = (bf16*)(w + 393216);              // 131072 -> 524288
    bf16*  Wob  = (bf16*)(w + 524288);              // 131072 -> 655360
    float* Yp   = (float*)(w + 655360);             // 8 MiB  -> 9043968
    float* Zp   = (float*)(w + 9043968);            // 8 MiB  -> 17432576
    float* Psum = (float*)(w + 17432576);           // 512 KiB -> 17956864
    float* Ssum = (float*)(w + 17956864);           // 512 KiB -> 18481152
    float* Carry= (float*)(w + 18481152);           // 512 KiB -> 19005440
    float* zpg  = (float*)(w + 19005440);           // 4 KiB
    bf16*  cwp  = (bf16*)(w + 19009536);            // 8 KiB
    float* cbl  = (float*)(w + 19017728);           // 4 KiB

    hipLaunchKernelGGL(k0_prep,     dim3(1048), dim3(256), 0, stream,
                       in_proj_w, out_proj_w, conv_w, conv_b,
                       Whg, Wlg, Wob, cwp, cbl, zpg);
    hipLaunchKernelGGL(k1_convproj, dim3(2048), dim3(256), 0, stream,
                       x, in_proj_b, A_log, Whg, Wlg, cwp, cbl, zpg,
                       Yp, Zp, Psum, Ssum);
    hipLaunchKernelGGL(k2_scan2,    dim3(8),    dim3(64),  0, stream, Psum, Ssum, Carry);
    hipLaunchKernelGGL(k3_scan_out, dim3(512),  dim3(512), 0, stream,
                       Yp, Zp, Carry, Wob, out_proj_b, out);
}

// Round 11
// 113.217 us; speedup vs baseline: 1.4436x; 1.4436x over previous
//
#include <hip/hip_runtime.h>
#include <cstdint>
#include <cstddef>

typedef __bf16 bf16;
typedef __attribute__((ext_vector_type(4))) __bf16 bf16x4;
typedef __attribute__((ext_vector_type(8))) __bf16 bf16x8;
typedef __attribute__((ext_vector_type(4))) float f32x4;

#define EPS_C 1e-4f
#define SWZ(r) (((r) ^ ((r) >> 2)) & 3)

// light barrier: LDS visibility only, vmem loads stay in flight (no vmcnt drain)
#define BAR_LDS() do { asm volatile("s_waitcnt lgkmcnt(0)" ::: "memory"); \
                       __builtin_amdgcn_s_barrier(); } while (0)

// ================= K0: weights prep + zero page =================
// Whg: reduced in_proj hi bf16, COLUMN-PERMUTED (each 48-col group = 16 delta +
// 16 Bmean + 16 Cmean), chunk-major [k/32][n_new][k%32] = MFMA B-fragment order.
// Wlg: lo-part of the 64 delta rows only, [k/32][d][k%32].
// Wob: out_proj bf16 [dm][i].
__global__ __launch_bounds__(256) void k0_prep(const float* __restrict__ Wi,
    const float* __restrict__ Wo, bf16* __restrict__ Whg, bf16* __restrict__ Wlg,
    bf16* __restrict__ Wob, float* __restrict__ zpg)
{
    int idx = blockIdx.x * 256 + threadIdx.x;
    if (idx < 196608) {
        int nn = idx >> 10, k = idx & 1023;
        int wn = nn / 48, s = nn - wn * 48;
        if (s < 16) {
            int d = wn * 16 + s;
            float w = Wi[d * 1024 + k];
            bf16 h = (bf16)w;
            Whg[(k >> 5) * 6144 + nn * 32 + (k & 31)] = h;
            Wlg[(k >> 5) * 2048 + d * 32 + (k & 31)] = (bf16)(w - (float)h);
        } else if (s < 32) {
            int i = wn * 16 + (s - 16);
            float w = 0.5f * (Wi[(64 + 2 * i) * 1024 + k] + Wi[(65 + 2 * i) * 1024 + k]);
            Whg[(k >> 5) * 6144 + nn * 32 + (k & 31)] = (bf16)w;
        } else {
            int i = wn * 16 + (s - 32);
            float w = 0.5f * (Wi[(192 + 2 * i) * 1024 + k] + Wi[(193 + 2 * i) * 1024 + k]);
            Whg[(k >> 5) * 6144 + nn * 32 + (k & 31)] = (bf16)w;
        }
    } else if (idx < 262144) {
        int j = idx - 196608;
        Wob[j] = (bf16)Wo[j];
    } else {
        int j = idx - 262144;
        if (j < 1024) zpg[j] = 0.f;
    }
}

// ================= K1: conv + MFMA in_proj (delta 3-pass, B/C 2-pass) + SSM + scan =================
// r6 structure (107us) + per-block CHUNK ROTATION (channel decorrelation) + 14-MFMA trim.
// 256 threads (4 waves), 4 blocks/CU. Block: 32t x 192n, BK=32, 32 chunks.
// Wave: 32t x 48n (permuted: 16d+16B+16C). W direct global->reg fragment-ordered.
__global__ __launch_bounds__(256, 4) void k1_convproj(
    const float* __restrict__ x, const float* __restrict__ conv_w,
    const float* __restrict__ conv_b, const float* __restrict__ in_proj_b,
    const float* __restrict__ A_log,
    const bf16* __restrict__ Whg, const bf16* __restrict__ Wlg,
    const float* __restrict__ zpg,
    float* __restrict__ Yp, float* __restrict__ Zp,
    float* __restrict__ Psum, float* __restrict__ Ssum)
{
    __shared__ char smem[28672];
    // xh buf p @ p*2048 | xl buf p @ 4096+p*2048 | cwT[4][1024] f32 @8192 | cbl @24576
    // epilogue overlay: res[32][196] f32 @0 (25088) | part @25088 (2048)

    const int tid  = threadIdx.x;
    const int lane = tid & 63;
    const int wn   = tid >> 6;
    const int fr   = lane & 15, fs = lane >> 4;
    const int b    = blockIdx.x >> 7;
    const int tc   = blockIdx.x & 127;
    const int t0   = tc * 32;
    const int rot  = (blockIdx.x * 5) & 31;  // chunk-schedule decorrelation

    // conv/staging mapping: thread -> (t-row ct, 4-ch slot cs)
    const int ct = tid >> 3, cs = tid & 7;
    const int gt = t0 + ct;
    const bool zrow = (gt == 4095);          // reference zero-pads last conv row
    const int xwo = ct * 64 + ((((cs >> 1) ^ SWZ(ct)) & 3) << 4) + (cs & 1) * 8;

    int aoff[2];
#pragma unroll
    for (int mi = 0; mi < 2; ++mi) {
        int r = mi * 16 + fr;
        aoff[mi] = r * 64 + ((fs ^ SWZ(r)) << 4);
    }

    // per-tap x pointers (OOB taps -> zero page)
    const float* rp[4];
#pragma unroll
    for (int dt = 0; dt < 4; ++dt) {
        int g = gt - 1 + dt;
        rp[dt] = (g >= 0 && g < 4096) ? (x + ((size_t)b * 4096 + g) * 1024 + cs * 4)
                                      : (zpg + cs * 4);
    }

    // W fragment offsets within a chunk
    const size_t wfo  = (size_t)(wn * 48 + fr) * 32 + fs * 8;   // hi (192 cols)
    const size_t wfol = (size_t)(wn * 16 + fr) * 32 + fs * 8;   // delta-lo (64 cols)

    // ---- preload conv tables to LDS (tap-major) ----
    {
        float* cwT = (float*)(smem + 8192);
        float* cbl = (float*)(smem + 24576);
        for (int p = tid; p < 1024; p += 256) {
            f32x4 w4 = *(const f32x4*)&conv_w[p * 4];
            cwT[p]        = w4.x;
            cwT[1024 + p] = w4.y;
            cwT[2048 + p] = w4.z;
            cwT[3072 + p] = w4.w;
        }
        ((f32x4*)cbl)[tid] = ((const f32x4*)conv_b)[tid];
    }

    f32x4  xr[4];
    bf16x8 wfh[3], wfl;
    f32x4  acc[2][3] = {};

    auto L = [&](int c) { return (c + rot) & 31; };

    auto fetch_x = [&](int lc) {
#pragma unroll
        for (int dt = 0; dt < 4; ++dt)
            xr[dt] = *(const f32x4*)(rp[dt] + lc * 32);
    };
    auto fetch_w = [&](int lc) {
        const bf16* ph = Whg + (size_t)lc * 6144 + wfo;
#pragma unroll
        for (int ni = 0; ni < 3; ++ni)
            wfh[ni] = *(const bf16x8*)(ph + ni * 512);
        wfl = *(const bf16x8*)(Wlg + (size_t)lc * 2048 + wfol);
    };
    auto conv = [&](int lc, int p) {         // conv logical chunk lc from xr -> LDS buf p
        char* xh = smem + p * 2048;
        char* xl = smem + 4096 + p * 2048;
        const float* cwT = (const float*)(smem + 8192);
        const float* cbl = (const float*)(smem + 24576);
        const int ch0 = lc * 32 + cs * 4;
        f32x4 w0 = *(const f32x4*)&cwT[ch0];
        f32x4 w1 = *(const f32x4*)&cwT[1024 + ch0];
        f32x4 w2 = *(const f32x4*)&cwT[2048 + ch0];
        f32x4 w3 = *(const f32x4*)&cwT[3072 + ch0];
        f32x4 bb = *(const f32x4*)&cbl[ch0];
        bf16x4 hi, lo;
#pragma unroll
        for (int j = 0; j < 4; ++j) {
            float v = bb[j];
            v = fmaf(w0[j], xr[0][j], v);
            v = fmaf(w1[j], xr[1][j], v);
            v = fmaf(w2[j], xr[2][j], v);
            v = fmaf(w3[j], xr[3][j], v);
            v = zrow ? 0.f : v;
            bf16 h = (bf16)v;
            hi[j] = h;
            lo[j] = (bf16)(v - (float)h);
        }
        *(bf16x4*)(xh + xwo) = hi;
        *(bf16x4*)(xl + xwo) = lo;
    };

    // ---- prologue ----
    fetch_x(L(0));
    fetch_w(L(0));
    __syncthreads();                         // conv tables visible
    conv(L(0), 0);
    fetch_x(L(1));
    __syncthreads();                         // buf0 visible

    auto body = [&](int c, int par) {
        const char* xh = smem + par * 2048;
        const char* xl = smem + 4096 + par * 2048;
        bf16x8 ah0 = *(const bf16x8*)(xh + aoff[0]);
        bf16x8 ah1 = *(const bf16x8*)(xh + aoff[1]);
        bf16x8 al0 = *(const bf16x8*)(xl + aoff[0]);
        bf16x8 al1 = *(const bf16x8*)(xl + aoff[1]);
        __builtin_amdgcn_s_setprio(1);
#pragma unroll
        for (int ni = 0; ni < 3; ++ni) {
            bf16x8 bh = wfh[ni];
            acc[0][ni] = __builtin_amdgcn_mfma_f32_16x16x32_bf16(ah0, bh, acc[0][ni], 0, 0, 0);
            acc[1][ni] = __builtin_amdgcn_mfma_f32_16x16x32_bf16(ah1, bh, acc[1][ni], 0, 0, 0);
            acc[0][ni] = __builtin_amdgcn_mfma_f32_16x16x32_bf16(al0, bh, acc[0][ni], 0, 0, 0);
            acc[1][ni] = __builtin_amdgcn_mfma_f32_16x16x32_bf16(al1, bh, acc[1][ni], 0, 0, 0);
        }
        acc[0][0] = __builtin_amdgcn_mfma_f32_16x16x32_bf16(ah0, wfl, acc[0][0], 0, 0, 0);
        acc[1][0] = __builtin_amdgcn_mfma_f32_16x16x32_bf16(ah1, wfl, acc[1][0], 0, 0, 0);
        __builtin_amdgcn_s_setprio(0);
        if (c + 1 < 32) {
            fetch_w(L(c + 1));               // in flight across barrier
            conv(L(c + 1), par ^ 1);         // xr = x(L(c+1)), write other buffer
            if (c + 2 < 32) fetch_x(L(c + 2));
        }
        BAR_LDS();                           // NO vmcnt drain
    };

#pragma unroll 1
    for (int cc = 0; cc < 32; cc += 2) {
        body(cc,     0);
        body(cc + 1, 1);
    }

    // ---- epilogue: acc -> res[32][196], SSM elementwise + chunk-local scan ----
    float* res = (float*)smem;
#pragma unroll
    for (int mi = 0; mi < 2; ++mi)
#pragma unroll
        for (int ni = 0; ni < 3; ++ni) {
            int col = wn * 48 + ni * 16 + fr;
#pragma unroll
            for (int r = 0; r < 4; ++r)
                res[(mi * 16 + fs * 4 + r) * 196 + col] = acc[mi][ni][r];
        }
    __syncthreads();

    float* part = (float*)(smem + 25088);    // [2][4][64]
    const int i  = lane;
    const int tg = tid >> 6;
    const float A  = -expf(A_log[i]);
    const float bd = in_proj_b[i];
    const float bB = 0.5f * (in_proj_b[64 + 2 * i] + in_proj_b[65 + 2 * i]);
    const float bC = 0.5f * (in_proj_b[192 + 2 * i] + in_proj_b[193 + 2 * i]);
    const bool tiny = fabsf(A) < EPS_C;
    const int dcol = (i >> 4) * 48 + (i & 15);   // un-permute columns
    float av[8], bv[8], cv[8];
#pragma unroll
    for (int r = 0; r < 8; ++r) {
        int t = tg * 8 + r;
        float d  = res[t * 196 + dcol] + bd;
        float Bm = res[t * 196 + dcol + 16] + bB;
        float Cm = res[t * 196 + dcol + 32] + bC;
        float delta = (d > 20.f) ? d : log1pf(expf(d));
        float dA = delta * A;
        float abar = expf(dA);
        float sc = tiny ? (1.f + dA * 0.5f + dA * dA * (1.f / 6.f)) : ((abar - 1.f) / A);
        av[r] = abar; bv[r] = sc * Bm; cv[r] = Cm;
    }
    float P = 1.f, S = 0.f;
#pragma unroll
    for (int r = 0; r < 8; ++r) { S = fmaf(av[r], S, bv[r]); P *= av[r]; }
    part[tg * 64 + i] = P;
    part[256 + tg * 64 + i] = S;
    __syncthreads();
    float h = 0.f, pp = 1.f;
#pragma unroll
    for (int g = 0; g < 3; ++g)
        if (g < tg) {
            float Pg = part[g * 64 + i], Sg = part[256 + g * 64 + i];
            h = fmaf(Pg, h, Sg);
            pp *= Pg;
        }
    size_t ob = ((size_t)b * 4096 + t0 + tg * 8) * 64 + i;
#pragma unroll
    for (int r = 0; r < 8; ++r) {
        h  = fmaf(av[r], h, bv[r]);          // chunk-local state
        pp *= av[r];                         // chunk-local prefix product
        Yp[ob + (size_t)r * 64] = cv[r] * h;
        Zp[ob + (size_t)r * 64] = cv[r] * pp;
    }
    if (tg == 3) {
        size_t o = ((size_t)b * 128 + tc) * 64 + i;
        Psum[o] = pp;
        Ssum[o] = h;
    }
}

// ================= K2: serial carry combine across 128 chunks =================
__global__ __launch_bounds__(64) void k2_scan2(const float* __restrict__ Psum,
    const float* __restrict__ Ssum, float* __restrict__ Carry)
{
    int b = blockIdx.x, i = threadIdx.x;
    float h = 0.f;
#pragma unroll 1
    for (int g = 0; g < 8; ++g) {
        size_t base = ((size_t)b * 128 + g * 16) * 64 + i;
        float Pv[16], Sv[16];
#pragma unroll
        for (int j = 0; j < 16; ++j) {
            Pv[j] = Psum[base + (size_t)j * 64];
            Sv[j] = Ssum[base + (size_t)j * 64];
        }
#pragma unroll
        for (int j = 0; j < 16; ++j) {
            Carry[base + (size_t)j * 64] = h;
            h = fmaf(Pv[j], h, Sv[j]);
        }
    }
}

// ================= K3: y = Yp + Zp*carry, fused out_proj MFMA =================
// 512 threads (8 waves). Block = 32-t chunk; wave: 32t x 128n.
__global__ __launch_bounds__(512) void k3_scan_out(
    const float* __restrict__ Yp, const float* __restrict__ Zp,
    const float* __restrict__ Carry, const bf16* __restrict__ Wob,
    const float* __restrict__ bo, float* __restrict__ out)
{
    __shared__ char sm3[4096];               // [32 t][64 i] bf16, swizzled

    const int tid  = threadIdx.x;
    const int lane = tid & 63;
    const int wv   = tid >> 6;
    const int b    = blockIdx.x >> 7;
    const int ch   = blockIdx.x & 127;
    const int t0   = ch * 32;

    const int i = lane, tg = wv;
    float cr = Carry[((size_t)b * 128 + ch) * 64 + i];
    size_t base = ((size_t)b * 4096 + t0 + tg * 4) * 64 + i;
#pragma unroll
    for (int r = 0; r < 4; ++r) {
        float y = Yp[base + (size_t)r * 64] + Zp[base + (size_t)r * 64] * cr;
        int t = tg * 4 + r;
        int off = t * 128 + ((((i >> 3) ^ (t & 7)) & 7) << 4) + (i & 7) * 2;
        *(bf16*)(sm3 + off) = (bf16)y;
    }
    __syncthreads();

    const int fr = lane & 15, fs = lane >> 4;
    bf16x8 afr[2][2];
#pragma unroll
    for (int mi = 0; mi < 2; ++mi)
#pragma unroll
        for (int ks = 0; ks < 2; ++ks) {
            int row = mi * 16 + fr;
            int slot = ks * 4 + fs;
            int off = row * 128 + (((slot ^ (row & 7)) & 7) << 4);
            afr[mi][ks] = *(const bf16x8*)(sm3 + off);
        }
    const int n0 = wv * 128;
#pragma unroll
    for (int ni = 0; ni < 8; ++ni) {
        int col = n0 + ni * 16 + fr;
        bf16x8 b0 = *(const bf16x8*)(Wob + (size_t)col * 64 + fs * 8);
        bf16x8 b1 = *(const bf16x8*)(Wob + (size_t)col * 64 + 32 + fs * 8);
        float bias = bo[col];
#pragma unroll
        for (int mi = 0; mi < 2; ++mi) {
            f32x4 a = {};
            a = __builtin_amdgcn_mfma_f32_16x16x32_bf16(afr[mi][0], b0, a, 0, 0, 0);
            a = __builtin_amdgcn_mfma_f32_16x16x32_bf16(afr[mi][1], b1, a, 0, 0, 0);
#pragma unroll
            for (int r = 0; r < 4; ++r) {
                int t = mi * 16 + fs * 4 + r;
                out[((size_t)b * 4096 + t0 + t) * 1024 + col] = a[r] + bias;
            }
        }
    }
}

extern "C" void kernel_launch(void* const* d_in, const int* in_sizes, int n_in,
                              void* d_out, int out_size, void* d_ws, size_t ws_size,
                              hipStream_t stream) {
    const float* x          = (const float*)d_in[0];
    const float* conv_w     = (const float*)d_in[1];
    const float* conv_b     = (const float*)d_in[2];
    const float* in_proj_w  = (const float*)d_in[3];
    const float* in_proj_b  = (const float*)d_in[4];
    const float* A_log      = (const float*)d_in[5];
    const float* out_proj_w = (const float*)d_in[6];
    const float* out_proj_b = (const float*)d_in[7];
    float* out = (float*)d_out;

    char* w = (char*)d_ws;
    bf16*  Whg  = (bf16*)w;                         // 393216
    bf16*  Wlg  = (bf16*)(w + 393216);              // 131072 -> 524288
    bf16*  Wob  = (bf16*)(w + 524288);              // 131072 -> 655360
    float* Yp   = (float*)(w + 655360);             // 8 MiB  -> 9043968
    float* Zp   = (float*)(w + 9043968);            // 8 MiB  -> 17432576
    float* Psum = (float*)(w + 17432576);           // 256 KiB -> 17694720
    float* Ssum = (float*)(w + 17694720);           // 256 KiB -> 17956864
    float* Carry= (float*)(w + 17956864);           // 256 KiB -> 18219008
    float* zpg  = (float*)(w + 18219008);           // 4 KiB zeroed

    hipLaunchKernelGGL(k0_prep,     dim3(1032), dim3(256), 0, stream,
                       in_proj_w, out_proj_w, Whg, Wlg, Wob, zpg);
    hipLaunchKernelGGL(k1_convproj, dim3(1024), dim3(256), 0, stream,
                       x, conv_w, conv_b, in_proj_b, A_log, Whg, Wlg, zpg,
                       Yp, Zp, Psum, Ssum);
    hipLaunchKernelGGL(k2_scan2,    dim3(8),    dim3(64),  0, stream, Psum, Ssum, Carry);
    hipLaunchKernelGGL(k3_scan_out, dim3(1024), dim3(512), 0, stream,
                       Yp, Zp, Carry, Wob, out_proj_b, out);
}

// Round 12
// 99.730 us; speedup vs baseline: 1.6389x; 1.1352x over previous
//
#include <hip/hip_runtime.h>
#include <cstdint>
#include <cstddef>

typedef __bf16 bf16;
typedef __attribute__((ext_vector_type(8))) __bf16 bf16x8;
typedef __attribute__((ext_vector_type(4))) float f32x4;

#define EPS_C 1e-4f
#define SWZ(r) (((r) ^ ((r) >> 2)) & 3)

// light barrier: LDS visibility only, vmem loads stay in flight (no vmcnt drain)
#define BAR_LDS() do { asm volatile("s_waitcnt lgkmcnt(0)" ::: "memory"); \
                       __builtin_amdgcn_s_barrier(); } while (0)

// ================= K0: weights prep + zero page =================
// Whg: reduced in_proj hi bf16, COLUMN-PERMUTED (each 48-col group = 16 delta +
// 16 Bmean + 16 Cmean), chunk-major [k/32][n_new][k%32] = MFMA B-fragment order.
// Wlg: lo-part of the 64 delta rows only, [k/32][d][k%32].
// Wob: out_proj bf16 [dm][i].
__global__ __launch_bounds__(256) void k0_prep(const float* __restrict__ Wi,
    const float* __restrict__ Wo, bf16* __restrict__ Whg, bf16* __restrict__ Wlg,
    bf16* __restrict__ Wob, float* __restrict__ zpg)
{
    int idx = blockIdx.x * 256 + threadIdx.x;
    if (idx < 196608) {
        int nn = idx >> 10, k = idx & 1023;
        int wn = nn / 48, s = nn - wn * 48;
        if (s < 16) {
            int d = wn * 16 + s;
            float w = Wi[d * 1024 + k];
            bf16 h = (bf16)w;
            Whg[(k >> 5) * 6144 + nn * 32 + (k & 31)] = h;
            Wlg[(k >> 5) * 2048 + d * 32 + (k & 31)] = (bf16)(w - (float)h);
        } else if (s < 32) {
            int i = wn * 16 + (s - 16);
            float w = 0.5f * (Wi[(64 + 2 * i) * 1024 + k] + Wi[(65 + 2 * i) * 1024 + k]);
            Whg[(k >> 5) * 6144 + nn * 32 + (k & 31)] = (bf16)w;
        } else {
            int i = wn * 16 + (s - 32);
            float w = 0.5f * (Wi[(192 + 2 * i) * 1024 + k] + Wi[(193 + 2 * i) * 1024 + k]);
            Whg[(k >> 5) * 6144 + nn * 32 + (k & 31)] = (bf16)w;
        }
    } else if (idx < 262144) {
        int j = idx - 196608;
        Wob[j] = (bf16)Wo[j];
    } else {
        int j = idx - 262144;
        if (j < 1024) zpg[j] = 0.f;
    }
}

// ================= K1: conv + MFMA in_proj (delta 3-pass, B/C 2-pass) + SSM + scan =================
// r11 pipeline, t-tile 64: 256 threads (4 waves), grid 512 (2 blocks/CU).
// Block: 64t x 192n, BK=32, 32 chunks. Wave: 64t x 48n -> acc[4][3], 28 MFMA/chunk.
// Per-CU VMEM halved vs r11 (W amortized over 2x rows).
__global__ __launch_bounds__(256) void k1_convproj(
    const float* __restrict__ x, const float* __restrict__ conv_w,
    const float* __restrict__ conv_b, const float* __restrict__ in_proj_b,
    const float* __restrict__ A_log,
    const bf16* __restrict__ Whg, const bf16* __restrict__ Wlg,
    const float* __restrict__ zpg,
    float* __restrict__ Yp, float* __restrict__ Zp,
    float* __restrict__ Psum, float* __restrict__ Ssum)
{
    __shared__ char smem[52224];
    // xh0@0 xh1@4096 | xl0@8192 xl1@12288 (each 4096 = 64 rows x 64B)
    // cwT[4][1024] f32 @16384 (16384) | cbl[1024] f32 @32768 (4096)
    // epilogue overlay: res[64][196] f32 @0 (50176) | part[2][4][64] @50176 (2048)

    const int tid  = threadIdx.x;
    const int lane = tid & 63;
    const int wn   = tid >> 6;
    const int fr   = lane & 15, fs = lane >> 4;
    const int b    = blockIdx.x >> 6;
    const int tc   = blockIdx.x & 63;
    const int t0   = tc * 64;
    const int rot  = (blockIdx.x * 5) & 31;

    // conv/staging mapping: thread -> (t-row ct 0..63, 8-ch slot cs 0..3)
    const int ct = tid >> 2, cs = tid & 3;
    const int gt = t0 + ct;
    const bool zrow = (gt == 4095);          // reference zero-pads last conv row
    const int xwo = ct * 64 + (((cs ^ SWZ(ct)) & 3) << 4);

    int aoff[4];
#pragma unroll
    for (int mi = 0; mi < 4; ++mi) {
        int r = mi * 16 + fr;
        aoff[mi] = r * 64 + ((fs ^ SWZ(r)) << 4);
    }

    // per-tap x pointers (OOB taps -> zero page)
    const float* rp[4];
#pragma unroll
    for (int dt = 0; dt < 4; ++dt) {
        int g = gt - 1 + dt;
        rp[dt] = (g >= 0 && g < 4096) ? (x + ((size_t)b * 4096 + g) * 1024 + cs * 8)
                                      : (zpg + cs * 8);
    }

    // W fragment offsets within a chunk
    const size_t wfo  = (size_t)(wn * 48 + fr) * 32 + fs * 8;   // hi (192 cols)
    const size_t wfol = (size_t)(wn * 16 + fr) * 32 + fs * 8;   // delta-lo (64 cols)

    // ---- preload conv tables to LDS (tap-major) ----
    {
        float* cwT = (float*)(smem + 16384);
        float* cbl = (float*)(smem + 32768);
        for (int p = tid; p < 1024; p += 256) {
            f32x4 w4 = *(const f32x4*)&conv_w[p * 4];
            cwT[p]        = w4.x;
            cwT[1024 + p] = w4.y;
            cwT[2048 + p] = w4.z;
            cwT[3072 + p] = w4.w;
        }
        ((f32x4*)cbl)[tid] = ((const f32x4*)conv_b)[tid];
    }

    f32x4  xr[4][2];
    bf16x8 wfh[3], wfl;
    f32x4  acc[4][3] = {};

    auto L = [&](int c) { return (c + rot) & 31; };

    auto fetch_x = [&](int lc) {
#pragma unroll
        for (int dt = 0; dt < 4; ++dt) {
            xr[dt][0] = *(const f32x4*)(rp[dt] + lc * 32);
            xr[dt][1] = *(const f32x4*)(rp[dt] + lc * 32 + 4);
        }
    };
    auto fetch_w = [&](int lc) {
        const bf16* ph = Whg + (size_t)lc * 6144 + wfo;
#pragma unroll
        for (int ni = 0; ni < 3; ++ni)
            wfh[ni] = *(const bf16x8*)(ph + ni * 512);
        wfl = *(const bf16x8*)(Wlg + (size_t)lc * 2048 + wfol);
    };
    auto conv = [&](int lc, int p) {         // conv logical chunk lc from xr -> LDS buf p
        char* xh = smem + p * 4096;
        char* xl = smem + 8192 + p * 4096;
        const float* cwT = (const float*)(smem + 16384);
        const float* cbl = (const float*)(smem + 32768);
        bf16x8 hi, lo;
#pragma unroll
        for (int s = 0; s < 2; ++s) {
            const int ch0 = lc * 32 + cs * 8 + s * 4;
            f32x4 w0 = *(const f32x4*)&cwT[ch0];
            f32x4 w1 = *(const f32x4*)&cwT[1024 + ch0];
            f32x4 w2 = *(const f32x4*)&cwT[2048 + ch0];
            f32x4 w3 = *(const f32x4*)&cwT[3072 + ch0];
            f32x4 bb = *(const f32x4*)&cbl[ch0];
#pragma unroll
            for (int j = 0; j < 4; ++j) {
                float v = bb[j];
                v = fmaf(w0[j], xr[0][s][j], v);
                v = fmaf(w1[j], xr[1][s][j], v);
                v = fmaf(w2[j], xr[2][s][j], v);
                v = fmaf(w3[j], xr[3][s][j], v);
                v = zrow ? 0.f : v;
                bf16 h = (bf16)v;
                hi[s * 4 + j] = h;
                lo[s * 4 + j] = (bf16)(v - (float)h);
            }
        }
        *(bf16x8*)(xh + xwo) = hi;
        *(bf16x8*)(xl + xwo) = lo;
    };

    // ---- prologue ----
    fetch_x(L(0));
    fetch_w(L(0));
    __syncthreads();                         // conv tables visible
    conv(L(0), 0);
    fetch_x(L(1));
    __syncthreads();                         // buf0 visible

    auto body = [&](int c, int par) {
        const char* xh = smem + par * 4096;
        const char* xl = smem + 8192 + par * 4096;
        bf16x8 ah[4], al[4];
#pragma unroll
        for (int mi = 0; mi < 4; ++mi) {
            ah[mi] = *(const bf16x8*)(xh + aoff[mi]);
            al[mi] = *(const bf16x8*)(xl + aoff[mi]);
        }
        __builtin_amdgcn_s_setprio(1);
#pragma unroll
        for (int ni = 0; ni < 3; ++ni) {
            bf16x8 bh = wfh[ni];
#pragma unroll
            for (int mi = 0; mi < 4; ++mi)
                acc[mi][ni] = __builtin_amdgcn_mfma_f32_16x16x32_bf16(ah[mi], bh, acc[mi][ni], 0, 0, 0);
#pragma unroll
            for (int mi = 0; mi < 4; ++mi)
                acc[mi][ni] = __builtin_amdgcn_mfma_f32_16x16x32_bf16(al[mi], bh, acc[mi][ni], 0, 0, 0);
        }
#pragma unroll
        for (int mi = 0; mi < 4; ++mi)
            acc[mi][0] = __builtin_amdgcn_mfma_f32_16x16x32_bf16(ah[mi], wfl, acc[mi][0], 0, 0, 0);
        __builtin_amdgcn_s_setprio(0);
        if (c + 1 < 32) {
            fetch_w(L(c + 1));               // in flight across barrier
            conv(L(c + 1), par ^ 1);         // xr = x(L(c+1)), write other buffer
            if (c + 2 < 32) fetch_x(L(c + 2));
        }
        BAR_LDS();                           // NO vmcnt drain
    };

#pragma unroll 1
    for (int cc = 0; cc < 32; cc += 2) {
        body(cc,     0);
        body(cc + 1, 1);
    }

    // ---- epilogue: acc -> res[64][196], SSM elementwise + chunk-local scan ----
    float* res = (float*)smem;
#pragma unroll
    for (int mi = 0; mi < 4; ++mi)
#pragma unroll
        for (int ni = 0; ni < 3; ++ni) {
            int col = wn * 48 + ni * 16 + fr;
#pragma unroll
            for (int r = 0; r < 4; ++r)
                res[(mi * 16 + fs * 4 + r) * 196 + col] = acc[mi][ni][r];
        }
    __syncthreads();

    float* part = (float*)(smem + 50176);    // [2][4][64]
    const int i  = lane;
    const int tg = tid >> 6;
    const float A  = -expf(A_log[i]);
    const float bd = in_proj_b[i];
    const float bB = 0.5f * (in_proj_b[64 + 2 * i] + in_proj_b[65 + 2 * i]);
    const float bC = 0.5f * (in_proj_b[192 + 2 * i] + in_proj_b[193 + 2 * i]);
    const bool tiny = fabsf(A) < EPS_C;
    const int dcol = (i >> 4) * 48 + (i & 15);   // un-permute columns
    float av[16], bv[16], cv[16];
#pragma unroll
    for (int r = 0; r < 16; ++r) {
        int t = tg * 16 + r;
        float d  = res[t * 196 + dcol] + bd;
        float Bm = res[t * 196 + dcol + 16] + bB;
        float Cm = res[t * 196 + dcol + 32] + bC;
        float delta = (d > 20.f) ? d : log1pf(expf(d));
        float dA = delta * A;
        float abar = expf(dA);
        float sc = tiny ? (1.f + dA * 0.5f + dA * dA * (1.f / 6.f)) : ((abar - 1.f) / A);
        av[r] = abar; bv[r] = sc * Bm; cv[r] = Cm;
    }
    float P = 1.f, S = 0.f;
#pragma unroll
    for (int r = 0; r < 16; ++r) { S = fmaf(av[r], S, bv[r]); P *= av[r]; }
    part[tg * 64 + i] = P;
    part[256 + tg * 64 + i] = S;
    __syncthreads();
    float h = 0.f, pp = 1.f;
#pragma unroll
    for (int g = 0; g < 3; ++g)
        if (g < tg) {
            float Pg = part[g * 64 + i], Sg = part[256 + g * 64 + i];
            h = fmaf(Pg, h, Sg);
            pp *= Pg;
        }
    size_t ob = ((size_t)b * 4096 + t0 + tg * 16) * 64 + i;
#pragma unroll
    for (int r = 0; r < 16; ++r) {
        h  = fmaf(av[r], h, bv[r]);          // chunk-local state
        pp *= av[r];                         // chunk-local prefix product
        Yp[ob + (size_t)r * 64] = cv[r] * h;
        Zp[ob + (size_t)r * 64] = cv[r] * pp;
    }
    if (tg == 3) {
        size_t o = ((size_t)b * 64 + tc) * 64 + i;
        Psum[o] = pp;
        Ssum[o] = h;
    }
}

// ================= K2: serial carry combine across 64 chunks =================
__global__ __launch_bounds__(64) void k2_scan2(const float* __restrict__ Psum,
    const float* __restrict__ Ssum, float* __restrict__ Carry)
{
    int b = blockIdx.x, i = threadIdx.x;
    float Pv[64], Sv[64];
#pragma unroll
    for (int c = 0; c < 64; ++c) {
        size_t o = ((size_t)(b * 64) + c) * 64 + i;
        Pv[c] = Psum[o]; Sv[c] = Ssum[o];
    }
    float h = 0.f;
#pragma unroll
    for (int c = 0; c < 64; ++c) {
        size_t o = ((size_t)(b * 64) + c) * 64 + i;
        Carry[o] = h;
        h = fmaf(Pv[c], h, Sv[c]);
    }
}

// ================= K3: y = Yp + Zp*carry, fused out_proj MFMA =================
// 512 threads (8 waves). Block = 64-t chunk; wave: 64t x 128n.
__global__ __launch_bounds__(512) void k3_scan_out(
    const float* __restrict__ Yp, const float* __restrict__ Zp,
    const float* __restrict__ Carry, const bf16* __restrict__ Wob,
    const float* __restrict__ bo, float* __restrict__ out)
{
    __shared__ char sm3[8192];               // [64 t][64 i] bf16, swizzled

    const int tid  = threadIdx.x;
    const int lane = tid & 63;
    const int wv   = tid >> 6;
    const int b    = blockIdx.x >> 6;
    const int ch   = blockIdx.x & 63;
    const int t0   = ch * 64;

    const int i = lane, tg = wv;
    float cr = Carry[((size_t)(b * 64) + ch) * 64 + i];
    size_t base = ((size_t)(b * 4096) + t0 + tg * 8) * 64 + i;
#pragma unroll
    for (int r = 0; r < 8; ++r) {
        float y = Yp[base + (size_t)r * 64] + Zp[base + (size_t)r * 64] * cr;
        int t = tg * 8 + r;
        int off = t * 128 + ((((i >> 3) ^ (t & 7)) & 7) << 4) + (i & 7) * 2;
        *(bf16*)(sm3 + off) = (bf16)y;
    }
    __syncthreads();

    const int fr = lane & 15, fs = lane >> 4;
    bf16x8 afr[4][2];
#pragma unroll
    for (int mi = 0; mi < 4; ++mi)
#pragma unroll
        for (int ks = 0; ks < 2; ++ks) {
            int row = mi * 16 + fr;
            int slot = ks * 4 + fs;
            int off = row * 128 + (((slot ^ (row & 7)) & 7) << 4);
            afr[mi][ks] = *(const bf16x8*)(sm3 + off);
        }
    const int n0 = wv * 128;
#pragma unroll
    for (int ni = 0; ni < 8; ++ni) {
        int col = n0 + ni * 16 + fr;
        bf16x8 b0 = *(const bf16x8*)(Wob + (size_t)col * 64 + fs * 8);
        bf16x8 b1 = *(const bf16x8*)(Wob + (size_t)col * 64 + 32 + fs * 8);
        float bias = bo[col];
#pragma unroll
        for (int mi = 0; mi < 4; ++mi) {
            f32x4 a = {};
            a = __builtin_amdgcn_mfma_f32_16x16x32_bf16(afr[mi][0], b0, a, 0, 0, 0);
            a = __builtin_amdgcn_mfma_f32_16x16x32_bf16(afr[mi][1], b1, a, 0, 0, 0);
#pragma unroll
            for (int r = 0; r < 4; ++r) {
                int t = mi * 16 + fs * 4 + r;
                out[((size_t)(b * 4096) + t0 + t) * 1024 + col] = a[r] + bias;
            }
        }
    }
}

extern "C" void kernel_launch(void* const* d_in, const int* in_sizes, int n_in,
                              void* d_out, int out_size, void* d_ws, size_t ws_size,
                              hipStream_t stream) {
    const float* x          = (const float*)d_in[0];
    const float* conv_w     = (const float*)d_in[1];
    const float* conv_b     = (const float*)d_in[2];
    const float* in_proj_w  = (const float*)d_in[3];
    const float* in_proj_b  = (const float*)d_in[4];
    const float* A_log      = (const float*)d_in[5];
    const float* out_proj_w = (const float*)d_in[6];
    const float* out_proj_b = (const float*)d_in[7];
    float* out = (float*)d_out;

    char* w = (char*)d_ws;
    bf16*  Whg  = (bf16*)w;                         // 393216
    bf16*  Wlg  = (bf16*)(w + 393216);              // 131072 -> 524288
    bf16*  Wob  = (bf16*)(w + 524288);              // 131072 -> 655360
    float* Yp   = (float*)(w + 655360);             // 8 MiB  -> 9043968
    float* Zp   = (float*)(w + 9043968);            // 8 MiB  -> 17432576
    float* Psum = (float*)(w + 17432576);           // 128 KiB -> 17563648
    float* Ssum = (float*)(w + 17563648);           // 128 KiB -> 17694720
    float* Carry= (float*)(w + 17694720);           // 128 KiB -> 17825792
    float* zpg  = (float*)(w + 17825792);           // 4 KiB zeroed

    hipLaunchKernelGGL(k0_prep,     dim3(1032), dim3(256), 0, stream,
                       in_proj_w, out_proj_w, Whg, Wlg, Wob, zpg);
    hipLaunchKernelGGL(k1_convproj, dim3(512),  dim3(256), 0, stream,
                       x, conv_w, conv_b, in_proj_b, A_log, Whg, Wlg, zpg,
                       Yp, Zp, Psum, Ssum);
    hipLaunchKernelGGL(k2_scan2,    dim3(8),    dim3(64),  0, stream, Psum, Ssum, Carry);
    hipLaunchKernelGGL(k3_scan_out, dim3(512),  dim3(512), 0, stream,
                       Yp, Zp, Carry, Wob, out_proj_b, out);
}

// Round 13
// 95.776 us; speedup vs baseline: 1.7065x; 1.0413x over previous
//
#include <hip/hip_runtime.h>
#include <cstdint>
#include <cstddef>

typedef __bf16 bf16;
typedef __attribute__((ext_vector_type(4))) __bf16 bf16x4;
typedef __attribute__((ext_vector_type(8))) __bf16 bf16x8;
typedef __attribute__((ext_vector_type(4))) float f32x4;

#define EPS_C 1e-4f
#define SWZ(r) (((r) ^ ((r) >> 2)) & 3)

// light barrier: LDS visibility only, vmem loads stay in flight (no vmcnt drain)
#define BAR_LDS() do { asm volatile("s_waitcnt lgkmcnt(0)" ::: "memory"); \
                       __builtin_amdgcn_s_barrier(); } while (0)

// ================= K0: weights prep + zero page =================
// Whg: reduced in_proj hi bf16, COLUMN-PERMUTED (each 48-col group = 16 delta +
// 16 Bmean + 16 Cmean), chunk-major [k/32][n_new][k%32] = MFMA B-fragment order.
// Wlg: lo-part of the 64 delta rows only, [k/32][d][k%32].
// Wob: out_proj bf16 [dm][i].
__global__ __launch_bounds__(256) void k0_prep(const float* __restrict__ Wi,
    const float* __restrict__ Wo, bf16* __restrict__ Whg, bf16* __restrict__ Wlg,
    bf16* __restrict__ Wob, float* __restrict__ zpg)
{
    int idx = blockIdx.x * 256 + threadIdx.x;
    if (idx < 196608) {
        int nn = idx >> 10, k = idx & 1023;
        int wn = nn / 48, s = nn - wn * 48;
        if (s < 16) {
            int d = wn * 16 + s;
            float w = Wi[d * 1024 + k];
            bf16 h = (bf16)w;
            Whg[(k >> 5) * 6144 + nn * 32 + (k & 31)] = h;
            Wlg[(k >> 5) * 2048 + d * 32 + (k & 31)] = (bf16)(w - (float)h);
        } else if (s < 32) {
            int i = wn * 16 + (s - 16);
            float w = 0.5f * (Wi[(64 + 2 * i) * 1024 + k] + Wi[(65 + 2 * i) * 1024 + k]);
            Whg[(k >> 5) * 6144 + nn * 32 + (k & 31)] = (bf16)w;
        } else {
            int i = wn * 16 + (s - 32);
            float w = 0.5f * (Wi[(192 + 2 * i) * 1024 + k] + Wi[(193 + 2 * i) * 1024 + k]);
            Whg[(k >> 5) * 6144 + nn * 32 + (k & 31)] = (bf16)w;
        }
    } else if (idx < 262144) {
        int j = idx - 196608;
        Wob[j] = (bf16)Wo[j];
    } else {
        int j = idx - 262144;
        if (j < 1024) zpg[j] = 0.f;
    }
}

// ================= K1: conv + MFMA in_proj (delta 3-pass, B/C 2-pass) + SSM + scan =================
// r12 structure, PAIR-ROW conv staging (5 shared taps / 2 rows -> x VMEM -37%).
// 256 threads (4 waves), grid 512. Block: 64t x 192n, BK=32, 32 chunks.
// Wave: 64t x 48n -> acc[4][3], 28 MFMA/chunk. xc tiles pitch 80 B (bank rotation).
__global__ __launch_bounds__(256) void k1_convproj(
    const float* __restrict__ x, const float* __restrict__ conv_w,
    const float* __restrict__ conv_b, const float* __restrict__ in_proj_b,
    const float* __restrict__ A_log,
    const bf16* __restrict__ Whg, const bf16* __restrict__ Wlg,
    const float* __restrict__ zpg,
    float* __restrict__ Yp, float* __restrict__ Zp,
    float* __restrict__ Psum, float* __restrict__ Ssum)
{
    __shared__ char smem[52224];
    // xh0@0 xh1@5120 | xl0@10240 xl1@15360 (each 5120 = 64 rows x 80 B)
    // cwT[4][1024] f32 @20480 (16384) | cbl[1024] f32 @36864 (4096)  (ends 40960)
    // epilogue overlay: res[64][196] f32 @0 (50176) | part[2][4][64] @50176 (2048)

    const int tid  = threadIdx.x;
    const int lane = tid & 63;
    const int wn   = tid >> 6;
    const int fr   = lane & 15, fs = lane >> 4;
    const int b    = blockIdx.x >> 6;
    const int tc   = blockIdx.x & 63;
    const int t0   = tc * 64;
    const int rot  = (blockIdx.x * 5) & 31;

    // pair-row conv mapping: thread -> (t-pair tp 0..31, 4-ch slot cq 0..7)
    const int tp = tid >> 3, cq = tid & 7;
    const int r0 = tp * 2, r1 = r0 + 1;
    const int gt0 = t0 + r0;
    const bool zrow1 = (gt0 + 1 == 4095);    // even rows can never be 4095
    const int woff0 = r0 * 80 + cq * 8;      // pitch-80: banks rotate across rows
    const int woff1 = r1 * 80 + cq * 8;

    int aoff[4];
#pragma unroll
    for (int mi = 0; mi < 4; ++mi) {
        int r = mi * 16 + fr;
        aoff[mi] = r * 80 + fs * 16;
    }

    // 5 tap pointers (rows gt0-1 .. gt0+3; OOB -> zero page)
    const float* rp[5];
#pragma unroll
    for (int dt = 0; dt < 5; ++dt) {
        int g = gt0 - 1 + dt;
        rp[dt] = (g >= 0 && g < 4096) ? (x + ((size_t)b * 4096 + g) * 1024 + cq * 4)
                                      : (zpg + cq * 4);
    }

    // W fragment offsets within a chunk
    const size_t wfo  = (size_t)(wn * 48 + fr) * 32 + fs * 8;   // hi (192 cols)
    const size_t wfol = (size_t)(wn * 16 + fr) * 32 + fs * 8;   // delta-lo (64 cols)

    // ---- preload conv tables to LDS (tap-major) ----
    {
        float* cwT = (float*)(smem + 20480);
        float* cbl = (float*)(smem + 36864);
        for (int p = tid; p < 1024; p += 256) {
            f32x4 w4 = *(const f32x4*)&conv_w[p * 4];
            cwT[p]        = w4.x;
            cwT[1024 + p] = w4.y;
            cwT[2048 + p] = w4.z;
            cwT[3072 + p] = w4.w;
        }
        ((f32x4*)cbl)[tid] = ((const f32x4*)conv_b)[tid];
    }

    f32x4  xr[5];
    bf16x8 wfh[3], wfl;
    f32x4  acc[4][3] = {};

    auto L = [&](int c) { return (c + rot) & 31; };

    auto fetch_x = [&](int lc) {
#pragma unroll
        for (int dt = 0; dt < 5; ++dt)
            xr[dt] = *(const f32x4*)(rp[dt] + lc * 32);
    };
    auto fetch_w = [&](int lc) {
        const bf16* ph = Whg + (size_t)lc * 6144 + wfo;
#pragma unroll
        for (int ni = 0; ni < 3; ++ni)
            wfh[ni] = *(const bf16x8*)(ph + ni * 512);
        wfl = *(const bf16x8*)(Wlg + (size_t)lc * 2048 + wfol);
    };
    auto conv = [&](int lc, int p) {         // conv logical chunk lc from xr -> LDS buf p
        char* xh = smem + p * 5120;
        char* xl = smem + 10240 + p * 5120;
        const float* cwT = (const float*)(smem + 20480);
        const float* cbl = (const float*)(smem + 36864);
        const int ch0 = lc * 32 + cq * 4;
        f32x4 w0 = *(const f32x4*)&cwT[ch0];
        f32x4 w1 = *(const f32x4*)&cwT[1024 + ch0];
        f32x4 w2 = *(const f32x4*)&cwT[2048 + ch0];
        f32x4 w3 = *(const f32x4*)&cwT[3072 + ch0];
        f32x4 bb = *(const f32x4*)&cbl[ch0];
        bf16x4 hi0, lo0, hi1, lo1;
#pragma unroll
        for (int j = 0; j < 4; ++j) {
            float v0 = bb[j];
            v0 = fmaf(w0[j], xr[0][j], v0);
            v0 = fmaf(w1[j], xr[1][j], v0);
            v0 = fmaf(w2[j], xr[2][j], v0);
            v0 = fmaf(w3[j], xr[3][j], v0);
            float v1 = bb[j];
            v1 = fmaf(w0[j], xr[1][j], v1);
            v1 = fmaf(w1[j], xr[2][j], v1);
            v1 = fmaf(w2[j], xr[3][j], v1);
            v1 = fmaf(w3[j], xr[4][j], v1);
            v1 = zrow1 ? 0.f : v1;
            bf16 h0 = (bf16)v0, h1 = (bf16)v1;
            hi0[j] = h0; lo0[j] = (bf16)(v0 - (float)h0);
            hi1[j] = h1; lo1[j] = (bf16)(v1 - (float)h1);
        }
        *(bf16x4*)(xh + woff0) = hi0;
        *(bf16x4*)(xh + woff1) = hi1;
        *(bf16x4*)(xl + woff0) = lo0;
        *(bf16x4*)(xl + woff1) = lo1;
    };

    // ---- prologue ----
    fetch_x(L(0));
    fetch_w(L(0));
    __syncthreads();                         // conv tables visible
    conv(L(0), 0);
    fetch_x(L(1));
    __syncthreads();                         // buf0 visible

    auto body = [&](int c, int par) {
        const char* xh = smem + par * 5120;
        const char* xl = smem + 10240 + par * 5120;
        bf16x8 ah[4], al[4];
#pragma unroll
        for (int mi = 0; mi < 4; ++mi) {
            ah[mi] = *(const bf16x8*)(xh + aoff[mi]);
            al[mi] = *(const bf16x8*)(xl + aoff[mi]);
        }
        __builtin_amdgcn_s_setprio(1);
#pragma unroll
        for (int ni = 0; ni < 3; ++ni) {
            bf16x8 bh = wfh[ni];
#pragma unroll
            for (int mi = 0; mi < 4; ++mi)
                acc[mi][ni] = __builtin_amdgcn_mfma_f32_16x16x32_bf16(ah[mi], bh, acc[mi][ni], 0, 0, 0);
#pragma unroll
            for (int mi = 0; mi < 4; ++mi)
                acc[mi][ni] = __builtin_amdgcn_mfma_f32_16x16x32_bf16(al[mi], bh, acc[mi][ni], 0, 0, 0);
        }
#pragma unroll
        for (int mi = 0; mi < 4; ++mi)
            acc[mi][0] = __builtin_amdgcn_mfma_f32_16x16x32_bf16(ah[mi], wfl, acc[mi][0], 0, 0, 0);
        __builtin_amdgcn_s_setprio(0);
        if (c + 1 < 32) {
            fetch_w(L(c + 1));               // in flight across barrier
            conv(L(c + 1), par ^ 1);         // xr = x(L(c+1)), write other buffer
            if (c + 2 < 32) fetch_x(L(c + 2));
        }
        BAR_LDS();                           // NO vmcnt drain
    };

#pragma unroll 1
    for (int cc = 0; cc < 32; cc += 2) {
        body(cc,     0);
        body(cc + 1, 1);
    }

    // ---- epilogue: acc -> res[64][196], SSM elementwise + chunk-local scan ----
    float* res = (float*)smem;
#pragma unroll
    for (int mi = 0; mi < 4; ++mi)
#pragma unroll
        for (int ni = 0; ni < 3; ++ni) {
            int col = wn * 48 + ni * 16 + fr;
#pragma unroll
            for (int r = 0; r < 4; ++r)
                res[(mi * 16 + fs * 4 + r) * 196 + col] = acc[mi][ni][r];
        }
    __syncthreads();

    float* part = (float*)(smem + 50176);    // [2][4][64]
    const int i  = lane;
    const int tg = tid >> 6;
    const float A  = -expf(A_log[i]);
    const float bd = in_proj_b[i];
    const float bB = 0.5f * (in_proj_b[64 + 2 * i] + in_proj_b[65 + 2 * i]);
    const float bC = 0.5f * (in_proj_b[192 + 2 * i] + in_proj_b[193 + 2 * i]);
    const bool tiny = fabsf(A) < EPS_C;
    const int dcol = (i >> 4) * 48 + (i & 15);   // un-permute columns
    float av[16], bv[16], cv[16];
#pragma unroll
    for (int r = 0; r < 16; ++r) {
        int t = tg * 16 + r;
        float d  = res[t * 196 + dcol] + bd;
        float Bm = res[t * 196 + dcol + 16] + bB;
        float Cm = res[t * 196 + dcol + 32] + bC;
        float delta = (d > 20.f) ? d : log1pf(expf(d));
        float dA = delta * A;
        float abar = expf(dA);
        float sc = tiny ? (1.f + dA * 0.5f + dA * dA * (1.f / 6.f)) : ((abar - 1.f) / A);
        av[r] = abar; bv[r] = sc * Bm; cv[r] = Cm;
    }
    float P = 1.f, S = 0.f;
#pragma unroll
    for (int r = 0; r < 16; ++r) { S = fmaf(av[r], S, bv[r]); P *= av[r]; }
    part[tg * 64 + i] = P;
    part[256 + tg * 64 + i] = S;
    __syncthreads();
    float h = 0.f, pp = 1.f;
#pragma unroll
    for (int g = 0; g < 3; ++g)
        if (g < tg) {
            float Pg = part[g * 64 + i], Sg = part[256 + g * 64 + i];
            h = fmaf(Pg, h, Sg);
            pp *= Pg;
        }
    size_t ob = ((size_t)b * 4096 + t0 + tg * 16) * 64 + i;
#pragma unroll
    for (int r = 0; r < 16; ++r) {
        h  = fmaf(av[r], h, bv[r]);          // chunk-local state
        pp *= av[r];                         // chunk-local prefix product
        Yp[ob + (size_t)r * 64] = cv[r] * h;
        Zp[ob + (size_t)r * 64] = cv[r] * pp;
    }
    if (tg == 3) {
        size_t o = ((size_t)b * 64 + tc) * 64 + i;
        Psum[o] = pp;
        Ssum[o] = h;
    }
}

// ================= K2: serial carry combine across 64 chunks =================
__global__ __launch_bounds__(64) void k2_scan2(const float* __restrict__ Psum,
    const float* __restrict__ Ssum, float* __restrict__ Carry)
{
    int b = blockIdx.x, i = threadIdx.x;
    float Pv[64], Sv[64];
#pragma unroll
    for (int c = 0; c < 64; ++c) {
        size_t o = ((size_t)(b * 64) + c) * 64 + i;
        Pv[c] = Psum[o]; Sv[c] = Ssum[o];
    }
    float h = 0.f;
#pragma unroll
    for (int c = 0; c < 64; ++c) {
        size_t o = ((size_t)(b * 64) + c) * 64 + i;
        Carry[o] = h;
        h = fmaf(Pv[c], h, Sv[c]);
    }
}

// ================= K3: y = Yp + Zp*carry, fused out_proj MFMA =================
// 512 threads (8 waves). Block = 64-t chunk; wave: 64t x 128n.
__global__ __launch_bounds__(512) void k3_scan_out(
    const float* __restrict__ Yp, const float* __restrict__ Zp,
    const float* __restrict__ Carry, const bf16* __restrict__ Wob,
    const float* __restrict__ bo, float* __restrict__ out)
{
    __shared__ char sm3[8192];               // [64 t][64 i] bf16, swizzled

    const int tid  = threadIdx.x;
    const int lane = tid & 63;
    const int wv   = tid >> 6;
    const int b    = blockIdx.x >> 6;
    const int ch   = blockIdx.x & 63;
    const int t0   = ch * 64;

    const int i = lane, tg = wv;
    float cr = Carry[((size_t)(b * 64) + ch) * 64 + i];
    size_t base = ((size_t)(b * 4096) + t0 + tg * 8) * 64 + i;
#pragma unroll
    for (int r = 0; r < 8; ++r) {
        float y = Yp[base + (size_t)r * 64] + Zp[base + (size_t)r * 64] * cr;
        int t = tg * 8 + r;
        int off = t * 128 + ((((i >> 3) ^ (t & 7)) & 7) << 4) + (i & 7) * 2;
        *(bf16*)(sm3 + off) = (bf16)y;
    }
    __syncthreads();

    const int fr = lane & 15, fs = lane >> 4;
    bf16x8 afr[4][2];
#pragma unroll
    for (int mi = 0; mi < 4; ++mi)
#pragma unroll
        for (int ks = 0; ks < 2; ++ks) {
            int row = mi * 16 + fr;
            int slot = ks * 4 + fs;
            int off = row * 128 + (((slot ^ (row & 7)) & 7) << 4);
            afr[mi][ks] = *(const bf16x8*)(sm3 + off);
        }
    const int n0 = wv * 128;
#pragma unroll
    for (int ni = 0; ni < 8; ++ni) {
        int col = n0 + ni * 16 + fr;
        bf16x8 b0 = *(const bf16x8*)(Wob + (size_t)col * 64 + fs * 8);
        bf16x8 b1 = *(const bf16x8*)(Wob + (size_t)col * 64 + 32 + fs * 8);
        float bias = bo[col];
#pragma unroll
        for (int mi = 0; mi < 4; ++mi) {
            f32x4 a = {};
            a = __builtin_amdgcn_mfma_f32_16x16x32_bf16(afr[mi][0], b0, a, 0, 0, 0);
            a = __builtin_amdgcn_mfma_f32_16x16x32_bf16(afr[mi][1], b1, a, 0, 0, 0);
#pragma unroll
            for (int r = 0; r < 4; ++r) {
                int t = mi * 16 + fs * 4 + r;
                out[((size_t)(b * 4096) + t0 + t) * 1024 + col] = a[r] + bias;
            }
        }
    }
}

extern "C" void kernel_launch(void* const* d_in, const int* in_sizes, int n_in,
                              void* d_out, int out_size, void* d_ws, size_t ws_size,
                              hipStream_t stream) {
    const float* x          = (const float*)d_in[0];
    const float* conv_w     = (const float*)d_in[1];
    const float* conv_b     = (const float*)d_in[2];
    const float* in_proj_w  = (const float*)d_in[3];
    const float* in_proj_b  = (const float*)d_in[4];
    const float* A_log      = (const float*)d_in[5];
    const float* out_proj_w = (const float*)d_in[6];
    const float* out_proj_b = (const float*)d_in[7];
    float* out = (float*)d_out;

    char* w = (char*)d_ws;
    bf16*  Whg  = (bf16*)w;                         // 393216
    bf16*  Wlg  = (bf16*)(w + 393216);              // 131072 -> 524288
    bf16*  Wob  = (bf16*)(w + 524288);              // 131072 -> 655360
    float* Yp   = (float*)(w + 655360);             // 8 MiB  -> 9043968
    float* Zp   = (float*)(w + 9043968);            // 8 MiB  -> 17432576
    float* Psum = (float*)(w + 17432576);           // 128 KiB -> 17563648
    float* Ssum = (float*)(w + 17563648);           // 128 KiB -> 17694720
    float* Carry= (float*)(w + 17694720);           // 128 KiB -> 17825792
    float* zpg  = (float*)(w + 17825792);           // 4 KiB zeroed

    hipLaunchKernelGGL(k0_prep,     dim3(1032), dim3(256), 0, stream,
                       in_proj_w, out_proj_w, Whg, Wlg, Wob, zpg);
    hipLaunchKernelGGL(k1_convproj, dim3(512),  dim3(256), 0, stream,
                       x, conv_w, conv_b, in_proj_b, A_log, Whg, Wlg, zpg,
                       Yp, Zp, Psum, Ssum);
    hipLaunchKernelGGL(k2_scan2,    dim3(8),    dim3(64),  0, stream, Psum, Ssum, Carry);
    hipLaunchKernelGGL(k3_scan_out, dim3(512),  dim3(512), 0, stream,
                       Yp, Zp, Carry, Wob, out_proj_b, out);
}

// Round 14
// 91.164 us; speedup vs baseline: 1.7929x; 1.0506x over previous
//
#include <hip/hip_runtime.h>
#include <cstdint>
#include <cstddef>

typedef __bf16 bf16;
typedef __attribute__((ext_vector_type(4))) __bf16 bf16x4;
typedef __attribute__((ext_vector_type(8))) __bf16 bf16x8;
typedef __attribute__((ext_vector_type(4))) float f32x4;
typedef __attribute__((ext_vector_type(2))) _Float16 f16x2;

#define EPS_C 1e-4f
#define SWZ(r) (((r) ^ ((r) >> 2)) & 3)

// light barrier: LDS visibility only, vmem loads stay in flight (no vmcnt drain)
#define BAR_LDS() do { asm volatile("s_waitcnt lgkmcnt(0)" ::: "memory"); \
                       __builtin_amdgcn_s_barrier(); } while (0)

// ================= K0: weights prep + zero page =================
// Whg: reduced in_proj hi bf16, COLUMN-PERMUTED (each 48-col group = 16 delta +
// 16 Bmean + 16 Cmean), chunk-major [k/32][n_new][k%32] = MFMA B-fragment order.
// Wlg: lo-part of the 64 delta rows only, [k/32][d][k%32].
// Wob: out_proj bf16 [dm][i].
__global__ __launch_bounds__(256) void k0_prep(const float* __restrict__ Wi,
    const float* __restrict__ Wo, bf16* __restrict__ Whg, bf16* __restrict__ Wlg,
    bf16* __restrict__ Wob, float* __restrict__ zpg)
{
    int idx = blockIdx.x * 256 + threadIdx.x;
    if (idx < 196608) {
        int nn = idx >> 10, k = idx & 1023;
        int wn = nn / 48, s = nn - wn * 48;
        if (s < 16) {
            int d = wn * 16 + s;
            float w = Wi[d * 1024 + k];
            bf16 h = (bf16)w;
            Whg[(k >> 5) * 6144 + nn * 32 + (k & 31)] = h;
            Wlg[(k >> 5) * 2048 + d * 32 + (k & 31)] = (bf16)(w - (float)h);
        } else if (s < 32) {
            int i = wn * 16 + (s - 16);
            float w = 0.5f * (Wi[(64 + 2 * i) * 1024 + k] + Wi[(65 + 2 * i) * 1024 + k]);
            Whg[(k >> 5) * 6144 + nn * 32 + (k & 31)] = (bf16)w;
        } else {
            int i = wn * 16 + (s - 32);
            float w = 0.5f * (Wi[(192 + 2 * i) * 1024 + k] + Wi[(193 + 2 * i) * 1024 + k]);
            Whg[(k >> 5) * 6144 + nn * 32 + (k & 31)] = (bf16)w;
        }
    } else if (idx < 262144) {
        int j = idx - 196608;
        Wob[j] = (bf16)Wo[j];
    } else {
        int j = idx - 262144;
        if (j < 1024) zpg[j] = 0.f;
    }
}

// ================= K1: conv + MFMA in_proj (delta 3-pass, B/C 2-pass) + SSM + scan =================
// t-tile 128, 512 threads (2 t-halves x 4 n-quarters), grid 256 = 1 block/CU.
// The wt-pair waves share W lines -> L1 dedup -> W L2-traffic per CU halves.
// Pair-row conv staging; xc tiles pitch 80 B; one light barrier/chunk.
__global__ __launch_bounds__(512) void k1_convproj(
    const float* __restrict__ x, const float* __restrict__ conv_w,
    const float* __restrict__ conv_b, const float* __restrict__ in_proj_b,
    const float* __restrict__ A_log,
    const bf16* __restrict__ Whg, const bf16* __restrict__ Wlg,
    const float* __restrict__ zpg,
    f16x2* __restrict__ YZp,
    float* __restrict__ Psum, float* __restrict__ Ssum)
{
    __shared__ char smem[61440];
    // xh buf p @ p*10240 | xl buf p @ 20480+p*10240 (each 10240 = 128 rows x 80 B)
    // cwT[4][1024] f32 @40960 (16384) | cbl[1024] f32 @57344 (4096)
    // epilogue overlay: res[64][196] f32 @0 (50176) | part[2][8][64] @50176 (4096)

    const int tid  = threadIdx.x;
    const int lane = tid & 63;
    const int wv   = tid >> 6;               // 0..7
    const int wt   = wv >> 2, wn = wv & 3;
    const int fr   = lane & 15, fs = lane >> 4;
    const int b    = blockIdx.x >> 5;
    const int tc   = blockIdx.x & 31;
    const int t0   = tc * 128;
    const int rot  = (blockIdx.x * 5) & 31;

    // pair-row conv mapping: thread -> (t-pair tp 0..63, 4-ch slot cq 0..7)
    const int tp = tid >> 3, cq = tid & 7;
    const int r0 = tp * 2, r1 = r0 + 1;
    const int gt0 = t0 + r0;
    const bool zrow1 = (gt0 + 1 == 4095);    // even rows can never be 4095
    const int woff0 = r0 * 80 + cq * 8;      // pitch-80: banks rotate across rows
    const int woff1 = r1 * 80 + cq * 8;

    int aoff[4];
#pragma unroll
    for (int mi = 0; mi < 4; ++mi) {
        int r = wt * 64 + mi * 16 + fr;
        aoff[mi] = r * 80 + fs * 16;
    }

    // 5 tap pointers (rows gt0-1 .. gt0+3; OOB -> zero page)
    const float* rp[5];
#pragma unroll
    for (int dt = 0; dt < 5; ++dt) {
        int g = gt0 - 1 + dt;
        rp[dt] = (g >= 0 && g < 4096) ? (x + ((size_t)b * 4096 + g) * 1024 + cq * 4)
                                      : (zpg + cq * 4);
    }

    // W fragment offsets within a chunk (wt-pair waves read identical lines)
    const size_t wfo  = (size_t)(wn * 48 + fr) * 32 + fs * 8;   // hi (192 cols)
    const size_t wfol = (size_t)(wn * 16 + fr) * 32 + fs * 8;   // delta-lo (64 cols)

    // ---- preload conv tables to LDS (tap-major) ----
    {
        float* cwT = (float*)(smem + 40960);
        float* cbl = (float*)(smem + 57344);
        for (int p = tid; p < 1024; p += 512) {
            f32x4 w4 = *(const f32x4*)&conv_w[p * 4];
            cwT[p]        = w4.x;
            cwT[1024 + p] = w4.y;
            cwT[2048 + p] = w4.z;
            cwT[3072 + p] = w4.w;
        }
        if (tid < 256) ((f32x4*)cbl)[tid] = ((const f32x4*)conv_b)[tid];
    }

    f32x4  xr[5];
    bf16x8 wfh[3], wfl;
    f32x4  acc[4][3] = {};

    auto L = [&](int c) { return (c + rot) & 31; };

    auto fetch_x = [&](int lc) {
#pragma unroll
        for (int dt = 0; dt < 5; ++dt)
            xr[dt] = *(const f32x4*)(rp[dt] + lc * 32);
    };
    auto fetch_w = [&](int lc) {
        const bf16* ph = Whg + (size_t)lc * 6144 + wfo;
#pragma unroll
        for (int ni = 0; ni < 3; ++ni)
            wfh[ni] = *(const bf16x8*)(ph + ni * 512);
        wfl = *(const bf16x8*)(Wlg + (size_t)lc * 2048 + wfol);
    };
    auto conv = [&](int lc, int p) {         // conv logical chunk lc from xr -> LDS buf p
        char* xh = smem + p * 10240;
        char* xl = smem + 20480 + p * 10240;
        const float* cwT = (const float*)(smem + 40960);
        const float* cbl = (const float*)(smem + 57344);
        const int ch0 = lc * 32 + cq * 4;
        f32x4 w0 = *(const f32x4*)&cwT[ch0];
        f32x4 w1 = *(const f32x4*)&cwT[1024 + ch0];
        f32x4 w2 = *(const f32x4*)&cwT[2048 + ch0];
        f32x4 w3 = *(const f32x4*)&cwT[3072 + ch0];
        f32x4 bb = *(const f32x4*)&cbl[ch0];
        bf16x4 hi0, lo0, hi1, lo1;
#pragma unroll
        for (int j = 0; j < 4; ++j) {
            float v0 = bb[j];
            v0 = fmaf(w0[j], xr[0][j], v0);
            v0 = fmaf(w1[j], xr[1][j], v0);
            v0 = fmaf(w2[j], xr[2][j], v0);
            v0 = fmaf(w3[j], xr[3][j], v0);
            float v1 = bb[j];
            v1 = fmaf(w0[j], xr[1][j], v1);
            v1 = fmaf(w1[j], xr[2][j], v1);
            v1 = fmaf(w2[j], xr[3][j], v1);
            v1 = fmaf(w3[j], xr[4][j], v1);
            v1 = zrow1 ? 0.f : v1;
            bf16 h0 = (bf16)v0, h1 = (bf16)v1;
            hi0[j] = h0; lo0[j] = (bf16)(v0 - (float)h0);
            hi1[j] = h1; lo1[j] = (bf16)(v1 - (float)h1);
        }
        *(bf16x4*)(xh + woff0) = hi0;
        *(bf16x4*)(xh + woff1) = hi1;
        *(bf16x4*)(xl + woff0) = lo0;
        *(bf16x4*)(xl + woff1) = lo1;
    };

    // ---- prologue ----
    fetch_x(L(0));
    fetch_w(L(0));
    __syncthreads();                         // conv tables visible
    conv(L(0), 0);
    fetch_x(L(1));
    __syncthreads();                         // buf0 visible

    auto body = [&](int c, int par) {
        const char* xh = smem + par * 10240;
        const char* xl = smem + 20480 + par * 10240;
        bf16x8 ah[4], al[4];
#pragma unroll
        for (int mi = 0; mi < 4; ++mi) {
            ah[mi] = *(const bf16x8*)(xh + aoff[mi]);
            al[mi] = *(const bf16x8*)(xl + aoff[mi]);
        }
        __builtin_amdgcn_s_setprio(1);
#pragma unroll
        for (int ni = 0; ni < 3; ++ni) {
            bf16x8 bh = wfh[ni];
#pragma unroll
            for (int mi = 0; mi < 4; ++mi)
                acc[mi][ni] = __builtin_amdgcn_mfma_f32_16x16x32_bf16(ah[mi], bh, acc[mi][ni], 0, 0, 0);
#pragma unroll
            for (int mi = 0; mi < 4; ++mi)
                acc[mi][ni] = __builtin_amdgcn_mfma_f32_16x16x32_bf16(al[mi], bh, acc[mi][ni], 0, 0, 0);
        }
#pragma unroll
        for (int mi = 0; mi < 4; ++mi)
            acc[mi][0] = __builtin_amdgcn_mfma_f32_16x16x32_bf16(ah[mi], wfl, acc[mi][0], 0, 0, 0);
        __builtin_amdgcn_s_setprio(0);
        if (c + 1 < 32) {
            fetch_w(L(c + 1));               // in flight across barrier
            conv(L(c + 1), par ^ 1);         // xr = x(L(c+1)), write other buffer
            if (c + 2 < 32) fetch_x(L(c + 2));
        }
        BAR_LDS();                           // NO vmcnt drain
    };

#pragma unroll 1
    for (int cc = 0; cc < 32; cc += 2) {
        body(cc,     0);
        body(cc + 1, 1);
    }

    // ---- epilogue: two 64-row passes; res[64][196] overlay; SSM + chunk-local scan ----
    float* res  = (float*)smem;
    float* part = (float*)(smem + 50176);    // [2][8][64]
    const int i  = lane;
    const int tg = tid >> 6;                 // 0..7: 8 rows each within the 64-row half
    const float A  = -expf(A_log[i]);
    const float bd = in_proj_b[i];
    const float bB = 0.5f * (in_proj_b[64 + 2 * i] + in_proj_b[65 + 2 * i]);
    const float bC = 0.5f * (in_proj_b[192 + 2 * i] + in_proj_b[193 + 2 * i]);
    const bool tiny = fabsf(A) < EPS_C;
    const int dcol = (i >> 4) * 48 + (i & 15);   // un-permute columns

#pragma unroll 1
    for (int hh = 0; hh < 2; ++hh) {
        __syncthreads();                     // prior res/part consumers done
        if (wt == hh) {
#pragma unroll
            for (int mi = 0; mi < 4; ++mi)
#pragma unroll
                for (int ni = 0; ni < 3; ++ni) {
                    int col = wn * 48 + ni * 16 + fr;
#pragma unroll
                    for (int r = 0; r < 4; ++r)
                        res[(mi * 16 + fs * 4 + r) * 196 + col] = acc[mi][ni][r];
                }
        }
        __syncthreads();
        float av[8], bv[8], cv[8];
#pragma unroll
        for (int r = 0; r < 8; ++r) {
            int t = tg * 8 + r;
            float d  = res[t * 196 + dcol] + bd;
            float Bm = res[t * 196 + dcol + 16] + bB;
            float Cm = res[t * 196 + dcol + 32] + bC;
            float delta = (d > 20.f) ? d : log1pf(expf(d));
            float dA = delta * A;
            float abar = expf(dA);
            float sc = tiny ? (1.f + dA * 0.5f + dA * dA * (1.f / 6.f)) : ((abar - 1.f) / A);
            av[r] = abar; bv[r] = sc * Bm; cv[r] = Cm;
        }
        float P = 1.f, S = 0.f;
#pragma unroll
        for (int r = 0; r < 8; ++r) { S = fmaf(av[r], S, bv[r]); P *= av[r]; }
        part[tg * 64 + i] = P;
        part[512 + tg * 64 + i] = S;
        __syncthreads();
        float h = 0.f, pp = 1.f;
#pragma unroll
        for (int g = 0; g < 7; ++g)
            if (g < tg) {
                float Pg = part[g * 64 + i], Sg = part[512 + g * 64 + i];
                h = fmaf(Pg, h, Sg);
                pp *= Pg;
            }
        size_t ob = ((size_t)b * 4096 + t0 + hh * 64 + tg * 8) * 64 + i;
#pragma unroll
        for (int r = 0; r < 8; ++r) {
            h  = fmaf(av[r], h, bv[r]);      // 64-row-chunk-local state
            pp *= av[r];                     // 64-row-chunk-local prefix product
            f16x2 yz;
            yz[0] = (_Float16)(cv[r] * h);
            yz[1] = (_Float16)(cv[r] * pp);
            YZp[ob + (size_t)r * 64] = yz;
        }
        if (tg == 7) {
            size_t o = ((size_t)b * 64 + tc * 2 + hh) * 64 + i;
            Psum[o] = pp;
            Ssum[o] = h;
        }
    }
}

// ================= K2: serial carry combine across 64 chunks =================
__global__ __launch_bounds__(64) void k2_scan2(const float* __restrict__ Psum,
    const float* __restrict__ Ssum, float* __restrict__ Carry)
{
    int b = blockIdx.x, i = threadIdx.x;
    float Pv[64], Sv[64];
#pragma unroll
    for (int c = 0; c < 64; ++c) {
        size_t o = ((size_t)(b * 64) + c) * 64 + i;
        Pv[c] = Psum[o]; Sv[c] = Ssum[o];
    }
    float h = 0.f;
#pragma unroll
    for (int c = 0; c < 64; ++c) {
        size_t o = ((size_t)(b * 64) + c) * 64 + i;
        Carry[o] = h;
        h = fmaf(Pv[c], h, Sv[c]);
    }
}

// ================= K3: y = Y + Z*carry (f16 packed), fused out_proj MFMA =================
// 512 threads (8 waves). Block = 64-t chunk; wave: 64t x 128n.
__global__ __launch_bounds__(512) void k3_scan_out(
    const f16x2* __restrict__ YZp, const float* __restrict__ Carry,
    const bf16* __restrict__ Wob, const float* __restrict__ bo,
    float* __restrict__ out)
{
    __shared__ char sm3[8192];               // [64 t][64 i] bf16, swizzled

    const int tid  = threadIdx.x;
    const int lane = tid & 63;
    const int wv   = tid >> 6;
    const int b    = blockIdx.x >> 6;
    const int ch   = blockIdx.x & 63;
    const int t0   = ch * 64;

    const int i = lane, tg = wv;
    float cr = Carry[((size_t)(b * 64) + ch) * 64 + i];
    size_t base = ((size_t)(b * 4096) + t0 + tg * 8) * 64 + i;
#pragma unroll
    for (int r = 0; r < 8; ++r) {
        f16x2 yz = YZp[base + (size_t)r * 64];
        float y = (float)yz[0] + (float)yz[1] * cr;
        int t = tg * 8 + r;
        int off = t * 128 + ((((i >> 3) ^ (t & 7)) & 7) << 4) + (i & 7) * 2;
        *(bf16*)(sm3 + off) = (bf16)y;
    }
    __syncthreads();

    const int fr = lane & 15, fs = lane >> 4;
    bf16x8 afr[4][2];
#pragma unroll
    for (int mi = 0; mi < 4; ++mi)
#pragma unroll
        for (int ks = 0; ks < 2; ++ks) {
            int row = mi * 16 + fr;
            int slot = ks * 4 + fs;
            int off = row * 128 + (((slot ^ (row & 7)) & 7) << 4);
            afr[mi][ks] = *(const bf16x8*)(sm3 + off);
        }
    const int n0 = wv * 128;
#pragma unroll
    for (int ni = 0; ni < 8; ++ni) {
        int col = n0 + ni * 16 + fr;
        bf16x8 b0 = *(const bf16x8*)(Wob + (size_t)col * 64 + fs * 8);
        bf16x8 b1 = *(const bf16x8*)(Wob + (size_t)col * 64 + 32 + fs * 8);
        float bias = bo[col];
#pragma unroll
        for (int mi = 0; mi < 4; ++mi) {
            f32x4 a = {};
            a = __builtin_amdgcn_mfma_f32_16x16x32_bf16(afr[mi][0], b0, a, 0, 0, 0);
            a = __builtin_amdgcn_mfma_f32_16x16x32_bf16(afr[mi][1], b1, a, 0, 0, 0);
#pragma unroll
            for (int r = 0; r < 4; ++r) {
                int t = mi * 16 + fs * 4 + r;
                out[((size_t)(b * 4096) + t0 + t) * 1024 + col] = a[r] + bias;
            }
        }
    }
}

extern "C" void kernel_launch(void* const* d_in, const int* in_sizes, int n_in,
                              void* d_out, int out_size, void* d_ws, size_t ws_size,
                              hipStream_t stream) {
    const float* x          = (const float*)d_in[0];
    const float* conv_w     = (const float*)d_in[1];
    const float* conv_b     = (const float*)d_in[2];
    const float* in_proj_w  = (const float*)d_in[3];
    const float* in_proj_b  = (const float*)d_in[4];
    const float* A_log      = (const float*)d_in[5];
    const float* out_proj_w = (const float*)d_in[6];
    const float* out_proj_b = (const float*)d_in[7];
    float* out = (float*)d_out;

    char* w = (char*)d_ws;
    bf16*  Whg  = (bf16*)w;                         // 393216
    bf16*  Wlg  = (bf16*)(w + 393216);              // 131072 -> 524288
    bf16*  Wob  = (bf16*)(w + 524288);              // 131072 -> 655360
    f16x2* YZp  = (f16x2*)(w + 655360);             // 8 MiB  -> 9043968
    float* Psum = (float*)(w + 9043968);            // 128 KiB -> 9175040
    float* Ssum = (float*)(w + 9175040);            // 128 KiB -> 9306112
    float* Carry= (float*)(w + 9306112);            // 128 KiB -> 9437184
    float* zpg  = (float*)(w + 9437184);            // 4 KiB zeroed

    hipLaunchKernelGGL(k0_prep,     dim3(1032), dim3(256), 0, stream,
                       in_proj_w, out_proj_w, Whg, Wlg, Wob, zpg);
    hipLaunchKernelGGL(k1_convproj, dim3(256),  dim3(512), 0, stream,
                       x, conv_w, conv_b, in_proj_b, A_log, Whg, Wlg, zpg,
                       YZp, Psum, Ssum);
    hipLaunchKernelGGL(k2_scan2,    dim3(8),    dim3(64),  0, stream, Psum, Ssum, Carry);
    hipLaunchKernelGGL(k3_scan_out, dim3(512),  dim3(512), 0, stream,
                       YZp, Carry, Wob, out_proj_b, out);
}